// Round 13
// baseline (157.133 us; speedup 1.0000x reference)
//
#include <hip/hip_runtime.h>
#include <hip/hip_bf16.h>

#define SDIM 2048
#define BATCH 4
#define DMODEL 512
#define NH 8
#define NKV 2
#define HD 64

typedef __bf16 bf16x8 __attribute__((ext_vector_type(8)));
typedef float floatx16 __attribute__((ext_vector_type(16)));
typedef unsigned short u16;
typedef unsigned int u32;

#define MFMA32 __builtin_amdgcn_mfma_f32_32x32x16_bf16
#define ZERO16 {0.f,0.f,0.f,0.f,0.f,0.f,0.f,0.f,0.f,0.f,0.f,0.f,0.f,0.f,0.f,0.f}
// softmax scale with log2(e) folded: exp(s*0.125) = exp2(s*0.125*log2e)
#define QSCALE 0.18033688011112042f

__device__ __forceinline__ u16 f2bf(float f) {
  union { float f; u32 u; } a; a.f = f;
  u32 r = a.u + 0x7fffu + ((a.u >> 16) & 1u);
  return (u16)(r >> 16);
}
// pack two f32 -> (lo, hi) bf16 pair via v_cvt_pk_bf16_f32
__device__ __forceinline__ u32 pkbf(float lo, float hi) {
  __hip_bfloat162 h = __float22bfloat162_rn(float2{lo, hi});
  union { __hip_bfloat162 h; u32 u; } c; c.h = h;
  return c.u;
}

// ---- fused conversions: x fp32->bf16 (blocks 0..4095, coalesced float4);
// weights -> WT[1280][512] bf16 via LDS 64x64 tile transpose (blocks
// 4096..4255). R12 version (best measured). ----
__global__ __launch_bounds__(256) void cvt_kernel(const float* __restrict__ x,
                                                  const float* __restrict__ Wq,
                                                  const float* __restrict__ Wk,
                                                  const float* __restrict__ Wv,
                                                  const float* __restrict__ Wo,
                                                  u16* __restrict__ xb,
                                                  u16* __restrict__ WT) {
  __shared__ u16 lds[64 * 66];
  int bid = blockIdx.x;
  if (bid < 4096) {
    int i = bid * 256 + threadIdx.x;
    float4 v = reinterpret_cast<const float4*>(x)[i];
    uint2 o = {pkbf(v.x, v.y), pkbf(v.z, v.w)};
    reinterpret_cast<uint2*>(xb)[i] = o;
  } else {
    int t = bid - 4096;           // 0..159
    int tn = t >> 3, tk = t & 7;  // tn 0..19 (n-tiles), tk 0..7 (k-tiles)
    int n0 = tn * 64, k0 = tk * 64;
    const float* src; int nc0, w;
    if (n0 < 512)      { src = Wq; nc0 = n0;       w = 512; }
    else if (n0 < 640) { src = Wk; nc0 = n0 - 512; w = 128; }
    else if (n0 < 768) { src = Wv; nc0 = n0 - 640; w = 128; }
    else               { src = Wo; nc0 = n0 - 768; w = 512; }
    int c = threadIdx.x & 63, r4 = threadIdx.x >> 6;
#pragma unroll
    for (int j = 0; j < 16; ++j) {
      int r = r4 + 4 * j;   // k-offset
      lds[c * 66 + r] = f2bf(src[(size_t)(k0 + r) * w + nc0 + c]);
    }
    __syncthreads();
#pragma unroll
    for (int j = 0; j < 16; ++j) {
      int cc = r4 + 4 * j;  // n-offset
      WT[(size_t)(n0 + cc) * 512 + k0 + c] = lds[cc * 66 + c];
    }
  }
}

// ---- fused QKV projection: 128x128 tile, BK=64 (8 iters, HALF the barriers
// of BK=32; 16 MFMA + 16 ds_read per wave per barrier interval). LDS dbuf
// stride-72 (72 KB, 2 blocks/CU; stride-72 measured 0 conflicts in attn).
// Distance-1 register prefetch: loads issued at iter start, ds_write at iter
// end -> no barrier crossed by outstanding loads, latency hidden under the
// 16-MFMA block. 4 waves (2m x 2n), 2x2 acc/wave. Q scaled by QSCALE;
// Q/K head-major [B,nh,S,64]; V written TRANSPOSED [B,NKV,64,S].
__global__ __launch_bounds__(256, 2) void gemm_qkv_kernel(const u16* __restrict__ A,
                                                          const u16* __restrict__ WT,
                                                          const float* __restrict__ bq,
                                                          const float* __restrict__ bk,
                                                          const float* __restrict__ bv,
                                                          u16* __restrict__ Qb,
                                                          u16* __restrict__ Kb,
                                                          u16* __restrict__ Vt) {
  __shared__ __align__(16) u16 abuf[2][128 * 72];
  __shared__ __align__(16) u16 bbuf[2][128 * 72];
  int tid = threadIdx.x;
  int lane = tid & 63, wave = tid >> 6;
  int l31 = lane & 31, half = lane >> 5;
  int m0 = blockIdx.y * 128;
  int n0 = blockIdx.x * 128;
  int row = tid >> 1, kh = tid & 1;   // row 0..127, kh covers 32 of BK=64
  const u16* Asrc = A + (size_t)(m0 + row) * DMODEL + kh * 32;
  const u16* Bsrc = WT + (size_t)(n0 + row) * DMODEL + kh * 32;
  int wo = row * 72 + kh * 32;

  bf16x8 rA[4], rB[4];
#pragma unroll
  for (int j = 0; j < 4; ++j) {
    rA[j] = *(const bf16x8*)(Asrc + j * 8);
    rB[j] = *(const bf16x8*)(Bsrc + j * 8);
  }
#pragma unroll
  for (int j = 0; j < 4; ++j) {
    *(bf16x8*)(abuf[0] + wo + j * 8) = rA[j];
    *(bf16x8*)(bbuf[0] + wo + j * 8) = rB[j];
  }
  __syncthreads();

  floatx16 acc[2][2] = {{ZERO16, ZERO16}, {ZERO16, ZERO16}};
  int mw = (wave & 1) * 64, nw = (wave >> 1) * 64;
  for (int it = 0; it < 8; ++it) {
    if (it < 7) {
#pragma unroll
      for (int j = 0; j < 4; ++j) {
        rA[j] = *(const bf16x8*)(Asrc + (it + 1) * 64 + j * 8);
        rB[j] = *(const bf16x8*)(Bsrc + (it + 1) * 64 + j * 8);
      }
    }
    const u16* ab = abuf[it & 1];
    const u16* bbp = bbuf[it & 1];
#pragma unroll
    for (int ks = 0; ks < 4; ++ks) {
      int co = (2 * ks + half) * 8;
      bf16x8 a0 = *(const bf16x8*)(ab + (mw + l31) * 72 + co);
      bf16x8 a1 = *(const bf16x8*)(ab + (mw + 32 + l31) * 72 + co);
      bf16x8 b0 = *(const bf16x8*)(bbp + (nw + l31) * 72 + co);
      bf16x8 b1 = *(const bf16x8*)(bbp + (nw + 32 + l31) * 72 + co);
      acc[0][0] = MFMA32(a0, b0, acc[0][0], 0, 0, 0);
      acc[0][1] = MFMA32(a0, b1, acc[0][1], 0, 0, 0);
      acc[1][0] = MFMA32(a1, b0, acc[1][0], 0, 0, 0);
      acc[1][1] = MFMA32(a1, b1, acc[1][1], 0, 0, 0);
    }
    if (it < 7) {
#pragma unroll
      for (int j = 0; j < 4; ++j) {
        *(bf16x8*)(abuf[(it + 1) & 1] + wo + j * 8) = rA[j];
        *(bf16x8*)(bbuf[(it + 1) & 1] + wo + j * 8) = rB[j];
      }
    }
    __syncthreads();
  }

  int b4 = m0 >> 11;  // batch fixed per block (m-tile within one batch)
#pragma unroll
  for (int ns = 0; ns < 2; ++ns) {
    int col = n0 + nw + ns * 32 + l31;
    if (col >= 640) {
      // V: write transposed rows of Vt[b,kv,d,s] as ushort4 (4 consecutive s)
      int lc = col - 640;
      float bl = bv[lc];
      int hkv = lc >> 6, d = lc & 63;
      u16* vrow = Vt + ((size_t)(b4 * NKV + hkv) * HD + d) * SDIM;
#pragma unroll
      for (int ms = 0; ms < 2; ++ms) {
#pragma unroll
        for (int g = 0; g < 4; ++g) {
          int s = (m0 + mw + ms * 32 + 8 * g + 4 * half) & 2047;
          ushort4 t;
          t.x = f2bf(acc[ms][ns][4 * g + 0] + bl);
          t.y = f2bf(acc[ms][ns][4 * g + 1] + bl);
          t.z = f2bf(acc[ms][ns][4 * g + 2] + bl);
          t.w = f2bf(acc[ms][ns][4 * g + 3] + bl);
          *(ushort4*)(vrow + s) = t;
        }
      }
    } else {
      u16* outp; const float* bias; float scale; int nhreg, lc;
      if (col < 512) { outp = Qb; bias = bq; scale = QSCALE; nhreg = NH;  lc = col; }
      else           { outp = Kb; bias = bk; scale = 1.0f;   nhreg = NKV; lc = col - 512; }
      float bl = bias[lc];
      int h = lc >> 6, d = lc & 63;
      u16* base = outp + ((size_t)(b4 * nhreg + h) * SDIM) * HD + d;
#pragma unroll
      for (int ms = 0; ms < 2; ++ms) {
#pragma unroll
        for (int r = 0; r < 16; ++r) {
          int s = (m0 + mw + ms * 32 + (r & 3) + 8 * (r >> 2) + 4 * half) & 2047;
          base[(size_t)s * HD] = f2bf((acc[ms][ns][r] + bl) * scale);
        }
      }
    }
  }
}

// ---- O projection: 128x128 tile, BK=64, same pipeline, fp32 output ----
__global__ __launch_bounds__(256, 2) void gemm_out_kernel(const u16* __restrict__ A,
                                                          const u16* __restrict__ WTo,
                                                          const float* __restrict__ bo,
                                                          float* __restrict__ out) {
  __shared__ __align__(16) u16 abuf[2][128 * 72];
  __shared__ __align__(16) u16 bbuf[2][128 * 72];
  int tid = threadIdx.x;
  int lane = tid & 63, wave = tid >> 6;
  int l31 = lane & 31, half = lane >> 5;
  int m0 = blockIdx.y * 128;
  int n0 = blockIdx.x * 128;
  int row = tid >> 1, kh = tid & 1;
  const u16* Asrc = A + (size_t)(m0 + row) * DMODEL + kh * 32;
  const u16* Bsrc = WTo + (size_t)(n0 + row) * DMODEL + kh * 32;
  int wo = row * 72 + kh * 32;

  bf16x8 rA[4], rB[4];
#pragma unroll
  for (int j = 0; j < 4; ++j) {
    rA[j] = *(const bf16x8*)(Asrc + j * 8);
    rB[j] = *(const bf16x8*)(Bsrc + j * 8);
  }
#pragma unroll
  for (int j = 0; j < 4; ++j) {
    *(bf16x8*)(abuf[0] + wo + j * 8) = rA[j];
    *(bf16x8*)(bbuf[0] + wo + j * 8) = rB[j];
  }
  __syncthreads();

  floatx16 acc[2][2] = {{ZERO16, ZERO16}, {ZERO16, ZERO16}};
  int mw = (wave & 1) * 64, nw = (wave >> 1) * 64;
  for (int it = 0; it < 8; ++it) {
    if (it < 7) {
#pragma unroll
      for (int j = 0; j < 4; ++j) {
        rA[j] = *(const bf16x8*)(Asrc + (it + 1) * 64 + j * 8);
        rB[j] = *(const bf16x8*)(Bsrc + (it + 1) * 64 + j * 8);
      }
    }
    const u16* ab = abuf[it & 1];
    const u16* bbp = bbuf[it & 1];
#pragma unroll
    for (int ks = 0; ks < 4; ++ks) {
      int co = (2 * ks + half) * 8;
      bf16x8 a0 = *(const bf16x8*)(ab + (mw + l31) * 72 + co);
      bf16x8 a1 = *(const bf16x8*)(ab + (mw + 32 + l31) * 72 + co);
      bf16x8 b0 = *(const bf16x8*)(bbp + (nw + l31) * 72 + co);
      bf16x8 b1 = *(const bf16x8*)(bbp + (nw + 32 + l31) * 72 + co);
      acc[0][0] = MFMA32(a0, b0, acc[0][0], 0, 0, 0);
      acc[0][1] = MFMA32(a0, b1, acc[0][1], 0, 0, 0);
      acc[1][0] = MFMA32(a1, b0, acc[1][0], 0, 0, 0);
      acc[1][1] = MFMA32(a1, b1, acc[1][1], 0, 0, 0);
    }
    if (it < 7) {
#pragma unroll
      for (int j = 0; j < 4; ++j) {
        *(bf16x8*)(abuf[(it + 1) & 1] + wo + j * 8) = rA[j];
        *(bf16x8*)(bbuf[(it + 1) & 1] + wo + j * 8) = rB[j];
      }
    }
    __syncthreads();
  }

#pragma unroll
  for (int ns = 0; ns < 2; ++ns) {
    int n = n0 + nw + ns * 32 + l31;
    float bl = bo[n];
#pragma unroll
    for (int ms = 0; ms < 2; ++ms) {
#pragma unroll
      for (int r = 0; r < 16; ++r) {
        int m = m0 + mw + ms * 32 + (r & 3) + 8 * (r >> 2) + 4 * half;
        out[(size_t)m * DMODEL + n] = acc[ms][ns][r] + bl;
      }
    }
  }
}

// ---- flash attention, SOFTWARE-PIPELINED (R9/R12 exact, best measured):
// PV(t) and QK(t+1)+exp share the post-barrier region; K dbuf, V triple-buf;
// one barrier/iter; P in registers (swapped QK^T). 45 KB LDS. ----
__global__ __launch_bounds__(256, 2) void attn_kernel(const u16* __restrict__ Q,
                                                      const u16* __restrict__ K,
                                                      const u16* __restrict__ Vt,
                                                      u16* __restrict__ O) {
  __shared__ __align__(16) u16 kbuf[2][64 * 72];
  __shared__ __align__(16) u16 vbuf[3][64 * 72];
  int tid = threadIdx.x;
  int lane = tid & 63, wave = tid >> 6;
  int l31 = lane & 31, half = lane >> 5;
  int bh = blockIdx.y;
  int b = bh >> 3, h = bh & 7, kv = h >> 2;
  int q0 = blockIdx.x * 128 + wave * 32;
  const u16* Qh = Q + (size_t)(b * NH + h) * SDIM * HD;
  const u16* Kh = K + (size_t)(b * NKV + kv) * SDIM * HD;
  const u16* Vh = Vt + (size_t)(b * NKV + kv) * HD * SDIM;

  bf16x8 qf[4];
#pragma unroll
  for (int ks = 0; ks < 4; ++ks)
    qf[ks] = *(const bf16x8*)(Qh + (size_t)(q0 + l31) * HD + ks * 16 + half * 8);

  int ch = tid & 7, rr = tid >> 3;   // rr 0..31
  const u16* Ks0 = Kh + (size_t)(2 * rr) * HD + ch * 8;
  const u16* Ks1 = Kh + (size_t)(2 * rr + 1) * HD + ch * 8;
  const u16* Vs0 = Vh + (size_t)(2 * rr) * SDIM + ch * 8;
  const u16* Vs1 = Vh + (size_t)(2 * rr + 1) * SDIM + ch * 8;
  int w0 = rr * 72 + ch * 8, w1 = (rr + 32) * 72 + ch * 8;

  {
    bf16x8 k0 = *(const bf16x8*)Ks0;
    bf16x8 k1 = *(const bf16x8*)Ks1;
    bf16x8 v0 = *(const bf16x8*)Vs0;
    bf16x8 v1 = *(const bf16x8*)Vs1;
    *(bf16x8*)(kbuf[0] + w0) = k0; *(bf16x8*)(kbuf[0] + w1) = k1;
    *(bf16x8*)(vbuf[0] + w0) = v0; *(bf16x8*)(vbuf[0] + w1) = v1;
  }
  bf16x8 sK0 = *(const bf16x8*)(Ks0 + 4096);
  bf16x8 sK1 = *(const bf16x8*)(Ks1 + 4096);
  bf16x8 sV0 = *(const bf16x8*)(Vs0 + 64);
  bf16x8 sV1 = *(const bf16x8*)(Vs1 + 64);
  __syncthreads();

  floatx16 o0 = ZERO16, o1 = ZERO16;
  float sml = 0.0f;
  u32 pk[16];

  // prologue: QK(0) + exp + pack
  {
    floatx16 sa = ZERO16, sb = ZERO16;
#pragma unroll
    for (int ks = 0; ks < 4; ++ks) {
      int co = (2 * ks + half) * 8;
      bf16x8 kf0 = *(const bf16x8*)(kbuf[0] + l31 * 72 + co);
      bf16x8 kf1 = *(const bf16x8*)(kbuf[0] + (32 + l31) * 72 + co);
      sa = MFMA32(kf0, qf[ks], sa, 0, 0, 0);
      sb = MFMA32(kf1, qf[ks], sb, 0, 0, 0);
    }
#pragma unroll
    for (int r = 0; r < 16; ++r) {
      float p0 = __builtin_amdgcn_exp2f(sa[r]);
      float p1 = __builtin_amdgcn_exp2f(sb[r]);
      sml += p0 + p1;
      pk[r] = pkbf(p0, p1);
    }
  }

  int vp = 0;  // v-read parity for iter t
  for (int t = 0; t < 32; ++t) {
    int wp = vp + 1; if (wp == 3) wp = 0;   // v-write parity = (t+1)%3
    int kp = (t + 1) & 1;                   // k write+read parity for tile t+1
    if (t < 31) {
      u16* kn = kbuf[kp];
      u16* vn = vbuf[wp];
      *(bf16x8*)(kn + w0) = sK0; *(bf16x8*)(kn + w1) = sK1;
      *(bf16x8*)(vn + w0) = sV0; *(bf16x8*)(vn + w1) = sV1;
    }
    if (t < 30) {
      sK0 = *(const bf16x8*)(Ks0 + (size_t)(t + 2) * 4096);
      sK1 = *(const bf16x8*)(Ks1 + (size_t)(t + 2) * 4096);
      sV0 = *(const bf16x8*)(Vs0 + (t + 2) * 64);
      sV1 = *(const bf16x8*)(Vs1 + (t + 2) * 64);
    }
    __syncthreads();

    // PV(t): A-frag kc = pk[4kc+0..3] (lane-local), V from vbuf[vp]
    const u16* vb = vbuf[vp];
#pragma unroll
    for (int kc = 0; kc < 4; ++kc) {
      int co = (2 * kc + half) * 8;
      union { u32 u[4]; bf16x8 v; } pf;
      pf.u[0] = pk[4 * kc + 0]; pf.u[1] = pk[4 * kc + 1];
      pf.u[2] = pk[4 * kc + 2]; pf.u[3] = pk[4 * kc + 3];
      bf16x8 vf0 = *(const bf16x8*)(vb + l31 * 72 + co);
      bf16x8 vf1 = *(const bf16x8*)(vb + (32 + l31) * 72 + co);
      o0 = MFMA32(pf.v, vf0, o0, 0, 0, 0);
      o1 = MFMA32(pf.v, vf1, o1, 0, 0, 0);
    }

    // QK(t+1) + exp + pack, overlapped with PV(t) above (independent)
    if (t < 31) {
      const u16* kb = kbuf[kp];
      floatx16 sa = ZERO16, sb = ZERO16;
#pragma unroll
      for (int ks = 0; ks < 4; ++ks) {
        int co = (2 * ks + half) * 8;
        bf16x8 kf0 = *(const bf16x8*)(kb + l31 * 72 + co);
        bf16x8 kf1 = *(const bf16x8*)(kb + (32 + l31) * 72 + co);
        sa = MFMA32(kf0, qf[ks], sa, 0, 0, 0);
        sb = MFMA32(kf1, qf[ks], sb, 0, 0, 0);
      }
      u32 pknew[16];
#pragma unroll
      for (int r = 0; r < 16; ++r) {
        float p0 = __builtin_amdgcn_exp2f(sa[r]);
        float p1 = __builtin_amdgcn_exp2f(sb[r]);
        sml += p0 + p1;
        pknew[r] = pkbf(p0, p1);
      }
#pragma unroll
      for (int r = 0; r < 16; ++r) pk[r] = pknew[r];
    }
    vp = wp;
  }

  sml += __shfl_xor(sml, 32);

#pragma unroll
  for (int r = 0; r < 16; ++r) {
    int q = (r & 3) + 8 * (r >> 2) + 4 * half;
    float inv = 1.0f / __shfl(sml, q);
    int s = q0 + q;
    u32* dst = (u32*)(O + ((size_t)(b * SDIM + s) * DMODEL + h * HD));
    dst[l31] = pkbf(o0[r] * inv, o1[r] * inv);
  }
}

extern "C" void kernel_launch(void* const* d_in, const int* in_sizes, int n_in,
                              void* d_out, int out_size, void* d_ws, size_t ws_size,
                              hipStream_t stream) {
  const float* x  = (const float*)d_in[0];
  const float* Wq = (const float*)d_in[1];
  const float* bq = (const float*)d_in[2];
  const float* Wk = (const float*)d_in[3];
  const float* bk = (const float*)d_in[4];
  const float* Wv = (const float*)d_in[5];
  const float* bv = (const float*)d_in[6];
  const float* Wo = (const float*)d_in[7];
  const float* bo = (const float*)d_in[8];
  float* out = (float*)d_out;

  const size_t M = (size_t)BATCH * SDIM;  // 8192
  u16* xb  = (u16*)d_ws;                  // 8192*512
  u16* WT  = xb  + M * DMODEL;            // 1280*512
  u16* Qb  = WT  + 1280 * DMODEL;         // 8192*512  [B,NH,S,64]
  u16* Kb  = Qb  + M * DMODEL;            // 8192*128  [B,NKV,S,64]
  u16* VtB = Kb  + M * 128;               // 8192*128  [B,NKV,64,S]
  u16* Ab  = VtB + M * 128;               // 8192*512  [B,S,512]

  cvt_kernel<<<4096 + 160, 256, 0, stream>>>(x, Wq, Wk, Wv, Wo, xb, WT);
  gemm_qkv_kernel<<<dim3(768 / 128, M / 128), 256, 0, stream>>>(xb, WT, bq, bk, bv, Qb, Kb, VtB);
  attn_kernel<<<dim3(SDIM / 128, BATCH * NH), 256, 0, stream>>>(Qb, Kb, VtB, Ab);
  gemm_out_kernel<<<dim3(512 / 128, M / 128), 256, 0, stream>>>(Ab, WT + (size_t)768 * DMODEL, bo, out);
}

// Round 14
// 155.493 us; speedup vs baseline: 1.0105x; 1.0105x over previous
//
#include <hip/hip_runtime.h>
#include <hip/hip_bf16.h>

#define SDIM 2048
#define BATCH 4
#define DMODEL 512
#define NH 8
#define NKV 2
#define HD 64

typedef __bf16 bf16x8 __attribute__((ext_vector_type(8)));
typedef float floatx16 __attribute__((ext_vector_type(16)));
typedef unsigned short u16;
typedef unsigned int u32;

#define MFMA32 __builtin_amdgcn_mfma_f32_32x32x16_bf16
#define ZERO16 {0.f,0.f,0.f,0.f,0.f,0.f,0.f,0.f,0.f,0.f,0.f,0.f,0.f,0.f,0.f,0.f}
// softmax scale with log2(e) folded: exp(s*0.125) = exp2(s*0.125*log2e)
#define QSCALE 0.18033688011112042f

__device__ __forceinline__ u16 f2bf(float f) {
  union { float f; u32 u; } a; a.f = f;
  u32 r = a.u + 0x7fffu + ((a.u >> 16) & 1u);
  return (u16)(r >> 16);
}
// pack two f32 -> (lo, hi) bf16 pair via v_cvt_pk_bf16_f32
__device__ __forceinline__ u32 pkbf(float lo, float hi) {
  __hip_bfloat162 h = __float22bfloat162_rn(float2{lo, hi});
  union { __hip_bfloat162 h; u32 u; } c; c.h = h;
  return c.u;
}

// ---- fused conversions: x fp32->bf16 (blocks 0..4095, coalesced float4);
// weights -> WT[1280][512] bf16 via LDS 64x64 tile transpose (blocks
// 4096..4255). R12 version (best measured). ----
__global__ __launch_bounds__(256) void cvt_kernel(const float* __restrict__ x,
                                                  const float* __restrict__ Wq,
                                                  const float* __restrict__ Wk,
                                                  const float* __restrict__ Wv,
                                                  const float* __restrict__ Wo,
                                                  u16* __restrict__ xb,
                                                  u16* __restrict__ WT) {
  __shared__ u16 lds[64 * 66];
  int bid = blockIdx.x;
  if (bid < 4096) {
    int i = bid * 256 + threadIdx.x;
    float4 v = reinterpret_cast<const float4*>(x)[i];
    uint2 o = {pkbf(v.x, v.y), pkbf(v.z, v.w)};
    reinterpret_cast<uint2*>(xb)[i] = o;
  } else {
    int t = bid - 4096;           // 0..159
    int tn = t >> 3, tk = t & 7;  // tn 0..19 (n-tiles), tk 0..7 (k-tiles)
    int n0 = tn * 64, k0 = tk * 64;
    const float* src; int nc0, w;
    if (n0 < 512)      { src = Wq; nc0 = n0;       w = 512; }
    else if (n0 < 640) { src = Wk; nc0 = n0 - 512; w = 128; }
    else if (n0 < 768) { src = Wv; nc0 = n0 - 640; w = 128; }
    else               { src = Wo; nc0 = n0 - 768; w = 512; }
    int c = threadIdx.x & 63, r4 = threadIdx.x >> 6;
#pragma unroll
    for (int j = 0; j < 16; ++j) {
      int r = r4 + 4 * j;   // k-offset
      lds[c * 66 + r] = f2bf(src[(size_t)(k0 + r) * w + nc0 + c]);
    }
    __syncthreads();
#pragma unroll
    for (int j = 0; j < 16; ++j) {
      int cc = r4 + 4 * j;  // n-offset
      WT[(size_t)(n0 + cc) * 512 + k0 + c] = lds[cc * 66 + c];
    }
  }
}

// ---- fused QKV projection: 128x128 tile, BK=32, distance-2 register prefetch,
// LDS dbuf stride-40 (40 KB), 32x32 MFMA, 4 waves (2m x 2n), 2x2 acc/wave.
// R12 version (best measured; BK=64 was neutral-to-negative in R13).
// Q scaled by QSCALE; Q/K head-major [B,nh,S,64]; V TRANSPOSED [B,NKV,64,S].
__global__ __launch_bounds__(256, 2) void gemm_qkv_kernel(const u16* __restrict__ A,
                                                          const u16* __restrict__ WT,
                                                          const float* __restrict__ bq,
                                                          const float* __restrict__ bk,
                                                          const float* __restrict__ bv,
                                                          u16* __restrict__ Qb,
                                                          u16* __restrict__ Kb,
                                                          u16* __restrict__ Vt) {
  __shared__ __align__(16) u16 abuf[2][128 * 40];
  __shared__ __align__(16) u16 bbuf[2][128 * 40];
  int tid = threadIdx.x;
  int lane = tid & 63, wave = tid >> 6;
  int l31 = lane & 31, half = lane >> 5;
  int m0 = blockIdx.y * 128;
  int n0 = blockIdx.x * 128;
  int row = tid >> 2, ch = tid & 3;   // row 0..63, 4 chunks of 8 cover BK=32
  const u16* Asrc = A + (size_t)(m0 + row) * DMODEL + ch * 8;
  const u16* Bsrc = WT + (size_t)(n0 + row) * DMODEL + ch * 8;
  int wo = row * 40 + ch * 8;

  bf16x8 rA[2][2], rB[2][2];   // [slot][row-group g: rows r / r+64]
#pragma unroll
  for (int g = 0; g < 2; ++g) {
    rA[0][g] = *(const bf16x8*)(Asrc + (size_t)g * 64 * DMODEL);
    rB[0][g] = *(const bf16x8*)(Bsrc + (size_t)g * 64 * DMODEL);
    rA[1][g] = *(const bf16x8*)(Asrc + (size_t)g * 64 * DMODEL + 32);
    rB[1][g] = *(const bf16x8*)(Bsrc + (size_t)g * 64 * DMODEL + 32);
  }
#pragma unroll
  for (int g = 0; g < 2; ++g) {
    *(bf16x8*)(abuf[0] + wo + g * 64 * 40) = rA[0][g];
    *(bf16x8*)(bbuf[0] + wo + g * 64 * 40) = rB[0][g];
  }
  __syncthreads();

  floatx16 acc[2][2] = {{ZERO16, ZERO16}, {ZERO16, ZERO16}};
  int mw = (wave & 1) * 64, nw = (wave >> 1) * 64;
#pragma unroll 2
  for (int it = 0; it < 16; ++it) {
    if (it < 14) {
#pragma unroll
      for (int g = 0; g < 2; ++g) {
        rA[it & 1][g] = *(const bf16x8*)(Asrc + (size_t)g * 64 * DMODEL + (it + 2) * 32);
        rB[it & 1][g] = *(const bf16x8*)(Bsrc + (size_t)g * 64 * DMODEL + (it + 2) * 32);
      }
    }
    const u16* ab = abuf[it & 1];
    const u16* bbp = bbuf[it & 1];
#pragma unroll
    for (int ks = 0; ks < 2; ++ks) {
      int co = (2 * ks + half) * 8;
      bf16x8 a0 = *(const bf16x8*)(ab + (mw + l31) * 40 + co);
      bf16x8 a1 = *(const bf16x8*)(ab + (mw + 32 + l31) * 40 + co);
      bf16x8 b0 = *(const bf16x8*)(bbp + (nw + l31) * 40 + co);
      bf16x8 b1 = *(const bf16x8*)(bbp + (nw + 32 + l31) * 40 + co);
      acc[0][0] = MFMA32(a0, b0, acc[0][0], 0, 0, 0);
      acc[0][1] = MFMA32(a0, b1, acc[0][1], 0, 0, 0);
      acc[1][0] = MFMA32(a1, b0, acc[1][0], 0, 0, 0);
      acc[1][1] = MFMA32(a1, b1, acc[1][1], 0, 0, 0);
    }
    if (it < 15) {
#pragma unroll
      for (int g = 0; g < 2; ++g) {
        *(bf16x8*)(abuf[(it + 1) & 1] + wo + g * 64 * 40) = rA[(it + 1) & 1][g];
        *(bf16x8*)(bbuf[(it + 1) & 1] + wo + g * 64 * 40) = rB[(it + 1) & 1][g];
      }
    }
    __syncthreads();
  }

  int b4 = m0 >> 11;  // batch fixed per block (m-tile within one batch)
#pragma unroll
  for (int ns = 0; ns < 2; ++ns) {
    int col = n0 + nw + ns * 32 + l31;
    if (col >= 640) {
      // V: write transposed rows of Vt[b,kv,d,s] as ushort4 (4 consecutive s)
      int lc = col - 640;
      float bl = bv[lc];
      int hkv = lc >> 6, d = lc & 63;
      u16* vrow = Vt + ((size_t)(b4 * NKV + hkv) * HD + d) * SDIM;
#pragma unroll
      for (int ms = 0; ms < 2; ++ms) {
#pragma unroll
        for (int g = 0; g < 4; ++g) {
          int s = (m0 + mw + ms * 32 + 8 * g + 4 * half) & 2047;
          ushort4 t;
          t.x = f2bf(acc[ms][ns][4 * g + 0] + bl);
          t.y = f2bf(acc[ms][ns][4 * g + 1] + bl);
          t.z = f2bf(acc[ms][ns][4 * g + 2] + bl);
          t.w = f2bf(acc[ms][ns][4 * g + 3] + bl);
          *(ushort4*)(vrow + s) = t;
        }
      }
    } else {
      u16* outp; const float* bias; float scale; int nhreg, lc;
      if (col < 512) { outp = Qb; bias = bq; scale = QSCALE; nhreg = NH;  lc = col; }
      else           { outp = Kb; bias = bk; scale = 1.0f;   nhreg = NKV; lc = col - 512; }
      float bl = bias[lc];
      int h = lc >> 6, d = lc & 63;
      u16* base = outp + ((size_t)(b4 * nhreg + h) * SDIM) * HD + d;
#pragma unroll
      for (int ms = 0; ms < 2; ++ms) {
#pragma unroll
        for (int r = 0; r < 16; ++r) {
          int s = (m0 + mw + ms * 32 + (r & 3) + 8 * (r >> 2) + 4 * half) & 2047;
          base[(size_t)s * HD] = f2bf((acc[ms][ns][r] + bl) * scale);
        }
      }
    }
  }
}

// ---- O projection: 128x128 tile, BK=32, same pipeline, fp32 output ----
__global__ __launch_bounds__(256, 2) void gemm_out_kernel(const u16* __restrict__ A,
                                                          const u16* __restrict__ WTo,
                                                          const float* __restrict__ bo,
                                                          float* __restrict__ out) {
  __shared__ __align__(16) u16 abuf[2][128 * 40];
  __shared__ __align__(16) u16 bbuf[2][128 * 40];
  int tid = threadIdx.x;
  int lane = tid & 63, wave = tid >> 6;
  int l31 = lane & 31, half = lane >> 5;
  int m0 = blockIdx.y * 128;
  int n0 = blockIdx.x * 128;
  int row = tid >> 2, ch = tid & 3;
  const u16* Asrc = A + (size_t)(m0 + row) * DMODEL + ch * 8;
  const u16* Bsrc = WTo + (size_t)(n0 + row) * DMODEL + ch * 8;
  int wo = row * 40 + ch * 8;

  bf16x8 rA[2][2], rB[2][2];
#pragma unroll
  for (int g = 0; g < 2; ++g) {
    rA[0][g] = *(const bf16x8*)(Asrc + (size_t)g * 64 * DMODEL);
    rB[0][g] = *(const bf16x8*)(Bsrc + (size_t)g * 64 * DMODEL);
    rA[1][g] = *(const bf16x8*)(Asrc + (size_t)g * 64 * DMODEL + 32);
    rB[1][g] = *(const bf16x8*)(Bsrc + (size_t)g * 64 * DMODEL + 32);
  }
#pragma unroll
  for (int g = 0; g < 2; ++g) {
    *(bf16x8*)(abuf[0] + wo + g * 64 * 40) = rA[0][g];
    *(bf16x8*)(bbuf[0] + wo + g * 64 * 40) = rB[0][g];
  }
  __syncthreads();

  floatx16 acc[2][2] = {{ZERO16, ZERO16}, {ZERO16, ZERO16}};
  int mw = (wave & 1) * 64, nw = (wave >> 1) * 64;
#pragma unroll 2
  for (int it = 0; it < 16; ++it) {
    if (it < 14) {
#pragma unroll
      for (int g = 0; g < 2; ++g) {
        rA[it & 1][g] = *(const bf16x8*)(Asrc + (size_t)g * 64 * DMODEL + (it + 2) * 32);
        rB[it & 1][g] = *(const bf16x8*)(Bsrc + (size_t)g * 64 * DMODEL + (it + 2) * 32);
      }
    }
    const u16* ab = abuf[it & 1];
    const u16* bbp = bbuf[it & 1];
#pragma unroll
    for (int ks = 0; ks < 2; ++ks) {
      int co = (2 * ks + half) * 8;
      bf16x8 a0 = *(const bf16x8*)(ab + (mw + l31) * 40 + co);
      bf16x8 a1 = *(const bf16x8*)(ab + (mw + 32 + l31) * 40 + co);
      bf16x8 b0 = *(const bf16x8*)(bbp + (nw + l31) * 40 + co);
      bf16x8 b1 = *(const bf16x8*)(bbp + (nw + 32 + l31) * 40 + co);
      acc[0][0] = MFMA32(a0, b0, acc[0][0], 0, 0, 0);
      acc[0][1] = MFMA32(a0, b1, acc[0][1], 0, 0, 0);
      acc[1][0] = MFMA32(a1, b0, acc[1][0], 0, 0, 0);
      acc[1][1] = MFMA32(a1, b1, acc[1][1], 0, 0, 0);
    }
    if (it < 15) {
#pragma unroll
      for (int g = 0; g < 2; ++g) {
        *(bf16x8*)(abuf[(it + 1) & 1] + wo + g * 64 * 40) = rA[(it + 1) & 1][g];
        *(bf16x8*)(bbuf[(it + 1) & 1] + wo + g * 64 * 40) = rB[(it + 1) & 1][g];
      }
    }
    __syncthreads();
  }

#pragma unroll
  for (int ns = 0; ns < 2; ++ns) {
    int n = n0 + nw + ns * 32 + l31;
    float bl = bo[n];
#pragma unroll
    for (int ms = 0; ms < 2; ++ms) {
#pragma unroll
      for (int r = 0; r < 16; ++r) {
        int m = m0 + mw + ms * 32 + (r & 3) + 8 * (r >> 2) + 4 * half;
        out[(size_t)m * DMODEL + n] = acc[ms][ns][r] + bl;
      }
    }
  }
}

// ---- flash attention, SOFTWARE-PIPELINED (R9 body) + s_setprio around the
// MFMA region ONLY (isolating the variable R11 bundled with the load reorder;
// guide m191: setprio +4-7% on attn with phase-diverse waves). PV(t) and
// QK(t+1)+exp share the post-barrier region; K dbuf, V triple-buf; one
// barrier/iter; P in registers (swapped QK^T). 45 KB LDS. ----
__global__ __launch_bounds__(256, 2) void attn_kernel(const u16* __restrict__ Q,
                                                      const u16* __restrict__ K,
                                                      const u16* __restrict__ Vt,
                                                      u16* __restrict__ O) {
  __shared__ __align__(16) u16 kbuf[2][64 * 72];
  __shared__ __align__(16) u16 vbuf[3][64 * 72];
  int tid = threadIdx.x;
  int lane = tid & 63, wave = tid >> 6;
  int l31 = lane & 31, half = lane >> 5;
  int bh = blockIdx.y;
  int b = bh >> 3, h = bh & 7, kv = h >> 2;
  int q0 = blockIdx.x * 128 + wave * 32;
  const u16* Qh = Q + (size_t)(b * NH + h) * SDIM * HD;
  const u16* Kh = K + (size_t)(b * NKV + kv) * SDIM * HD;
  const u16* Vh = Vt + (size_t)(b * NKV + kv) * HD * SDIM;

  bf16x8 qf[4];
#pragma unroll
  for (int ks = 0; ks < 4; ++ks)
    qf[ks] = *(const bf16x8*)(Qh + (size_t)(q0 + l31) * HD + ks * 16 + half * 8);

  int ch = tid & 7, rr = tid >> 3;   // rr 0..31
  const u16* Ks0 = Kh + (size_t)(2 * rr) * HD + ch * 8;
  const u16* Ks1 = Kh + (size_t)(2 * rr + 1) * HD + ch * 8;
  const u16* Vs0 = Vh + (size_t)(2 * rr) * SDIM + ch * 8;
  const u16* Vs1 = Vh + (size_t)(2 * rr + 1) * SDIM + ch * 8;
  int w0 = rr * 72 + ch * 8, w1 = (rr + 32) * 72 + ch * 8;

  {
    bf16x8 k0 = *(const bf16x8*)Ks0;
    bf16x8 k1 = *(const bf16x8*)Ks1;
    bf16x8 v0 = *(const bf16x8*)Vs0;
    bf16x8 v1 = *(const bf16x8*)Vs1;
    *(bf16x8*)(kbuf[0] + w0) = k0; *(bf16x8*)(kbuf[0] + w1) = k1;
    *(bf16x8*)(vbuf[0] + w0) = v0; *(bf16x8*)(vbuf[0] + w1) = v1;
  }
  bf16x8 sK0 = *(const bf16x8*)(Ks0 + 4096);
  bf16x8 sK1 = *(const bf16x8*)(Ks1 + 4096);
  bf16x8 sV0 = *(const bf16x8*)(Vs0 + 64);
  bf16x8 sV1 = *(const bf16x8*)(Vs1 + 64);
  __syncthreads();

  floatx16 o0 = ZERO16, o1 = ZERO16;
  float sml = 0.0f;
  u32 pk[16];

  // prologue: QK(0) + exp + pack
  {
    floatx16 sa = ZERO16, sb = ZERO16;
#pragma unroll
    for (int ks = 0; ks < 4; ++ks) {
      int co = (2 * ks + half) * 8;
      bf16x8 kf0 = *(const bf16x8*)(kbuf[0] + l31 * 72 + co);
      bf16x8 kf1 = *(const bf16x8*)(kbuf[0] + (32 + l31) * 72 + co);
      sa = MFMA32(kf0, qf[ks], sa, 0, 0, 0);
      sb = MFMA32(kf1, qf[ks], sb, 0, 0, 0);
    }
#pragma unroll
    for (int r = 0; r < 16; ++r) {
      float p0 = __builtin_amdgcn_exp2f(sa[r]);
      float p1 = __builtin_amdgcn_exp2f(sb[r]);
      sml += p0 + p1;
      pk[r] = pkbf(p0, p1);
    }
  }

  int vp = 0;  // v-read parity for iter t
  for (int t = 0; t < 32; ++t) {
    int wp = vp + 1; if (wp == 3) wp = 0;   // v-write parity = (t+1)%3
    int kp = (t + 1) & 1;                   // k write+read parity for tile t+1
    if (t < 31) {
      u16* kn = kbuf[kp];
      u16* vn = vbuf[wp];
      *(bf16x8*)(kn + w0) = sK0; *(bf16x8*)(kn + w1) = sK1;
      *(bf16x8*)(vn + w0) = sV0; *(bf16x8*)(vn + w1) = sV1;
    }
    if (t < 30) {
      sK0 = *(const bf16x8*)(Ks0 + (size_t)(t + 2) * 4096);
      sK1 = *(const bf16x8*)(Ks1 + (size_t)(t + 2) * 4096);
      sV0 = *(const bf16x8*)(Vs0 + (t + 2) * 64);
      sV1 = *(const bf16x8*)(Vs1 + (t + 2) * 64);
    }
    __syncthreads();

    __builtin_amdgcn_s_setprio(1);
    // PV(t): A-frag kc = pk[4kc+0..3] (lane-local), V from vbuf[vp]
    const u16* vb = vbuf[vp];
#pragma unroll
    for (int kc = 0; kc < 4; ++kc) {
      int co = (2 * kc + half) * 8;
      union { u32 u[4]; bf16x8 v; } pf;
      pf.u[0] = pk[4 * kc + 0]; pf.u[1] = pk[4 * kc + 1];
      pf.u[2] = pk[4 * kc + 2]; pf.u[3] = pk[4 * kc + 3];
      bf16x8 vf0 = *(const bf16x8*)(vb + l31 * 72 + co);
      bf16x8 vf1 = *(const bf16x8*)(vb + (32 + l31) * 72 + co);
      o0 = MFMA32(pf.v, vf0, o0, 0, 0, 0);
      o1 = MFMA32(pf.v, vf1, o1, 0, 0, 0);
    }

    // QK(t+1) + exp + pack, overlapped with PV(t) above (independent)
    if (t < 31) {
      const u16* kb = kbuf[kp];
      floatx16 sa = ZERO16, sb = ZERO16;
#pragma unroll
      for (int ks = 0; ks < 4; ++ks) {
        int co = (2 * ks + half) * 8;
        bf16x8 kf0 = *(const bf16x8*)(kb + l31 * 72 + co);
        bf16x8 kf1 = *(const bf16x8*)(kb + (32 + l31) * 72 + co);
        sa = MFMA32(kf0, qf[ks], sa, 0, 0, 0);
        sb = MFMA32(kf1, qf[ks], sb, 0, 0, 0);
      }
      __builtin_amdgcn_s_setprio(0);
      u32 pknew[16];
#pragma unroll
      for (int r = 0; r < 16; ++r) {
        float p0 = __builtin_amdgcn_exp2f(sa[r]);
        float p1 = __builtin_amdgcn_exp2f(sb[r]);
        sml += p0 + p1;
        pknew[r] = pkbf(p0, p1);
      }
#pragma unroll
      for (int r = 0; r < 16; ++r) pk[r] = pknew[r];
    } else {
      __builtin_amdgcn_s_setprio(0);
    }
    vp = wp;
  }

  sml += __shfl_xor(sml, 32);

#pragma unroll
  for (int r = 0; r < 16; ++r) {
    int q = (r & 3) + 8 * (r >> 2) + 4 * half;
    float inv = 1.0f / __shfl(sml, q);
    int s = q0 + q;
    u32* dst = (u32*)(O + ((size_t)(b * SDIM + s) * DMODEL + h * HD));
    dst[l31] = pkbf(o0[r] * inv, o1[r] * inv);
  }
}

extern "C" void kernel_launch(void* const* d_in, const int* in_sizes, int n_in,
                              void* d_out, int out_size, void* d_ws, size_t ws_size,
                              hipStream_t stream) {
  const float* x  = (const float*)d_in[0];
  const float* Wq = (const float*)d_in[1];
  const float* bq = (const float*)d_in[2];
  const float* Wk = (const float*)d_in[3];
  const float* bk = (const float*)d_in[4];
  const float* Wv = (const float*)d_in[5];
  const float* bv = (const float*)d_in[6];
  const float* Wo = (const float*)d_in[7];
  const float* bo = (const float*)d_in[8];
  float* out = (float*)d_out;

  const size_t M = (size_t)BATCH * SDIM;  // 8192
  u16* xb  = (u16*)d_ws;                  // 8192*512
  u16* WT  = xb  + M * DMODEL;            // 1280*512
  u16* Qb  = WT  + 1280 * DMODEL;         // 8192*512  [B,NH,S,64]
  u16* Kb  = Qb  + M * DMODEL;            // 8192*128  [B,NKV,S,64]
  u16* VtB = Kb  + M * 128;               // 8192*128  [B,NKV,64,S]
  u16* Ab  = VtB + M * 128;               // 8192*512  [B,S,512]

  cvt_kernel<<<4096 + 160, 256, 0, stream>>>(x, Wq, Wk, Wv, Wo, xb, WT);
  gemm_qkv_kernel<<<dim3(768 / 128, M / 128), 256, 0, stream>>>(xb, WT, bq, bk, bv, Qb, Kb, VtB);
  attn_kernel<<<dim3(SDIM / 128, BATCH * NH), 256, 0, stream>>>(Qb, Kb, VtB, Ab);
  gemm_out_kernel<<<dim3(512 / 128, M / 128), 256, 0, stream>>>(Ab, WT + (size_t)768 * DMODEL, bo, out);
}

// Round 15
// 152.595 us; speedup vs baseline: 1.0297x; 1.0190x over previous
//
#include <hip/hip_runtime.h>
#include <hip/hip_bf16.h>

#define SDIM 2048
#define BATCH 4
#define DMODEL 512
#define NH 8
#define NKV 2
#define HD 64

typedef __bf16 bf16x8 __attribute__((ext_vector_type(8)));
typedef float floatx16 __attribute__((ext_vector_type(16)));
typedef unsigned short u16;
typedef unsigned int u32;

#define MFMA32 __builtin_amdgcn_mfma_f32_32x32x16_bf16
#define ZERO16 {0.f,0.f,0.f,0.f,0.f,0.f,0.f,0.f,0.f,0.f,0.f,0.f,0.f,0.f,0.f,0.f}
// softmax scale with log2(e) folded: exp(s*0.125) = exp2(s*0.125*log2e)
#define QSCALE 0.18033688011112042f

__device__ __forceinline__ u16 f2bf(float f) {
  union { float f; u32 u; } a; a.f = f;
  u32 r = a.u + 0x7fffu + ((a.u >> 16) & 1u);
  return (u16)(r >> 16);
}
// pack two f32 -> (lo, hi) bf16 pair via v_cvt_pk_bf16_f32
__device__ __forceinline__ u32 pkbf(float lo, float hi) {
  __hip_bfloat162 h = __float22bfloat162_rn(float2{lo, hi});
  union { __hip_bfloat162 h; u32 u; } c; c.h = h;
  return c.u;
}

// ---- fused conversions: x fp32->bf16 (blocks 0..4095, coalesced float4);
// weights -> WT[1280][512] bf16 via LDS 64x64 tile transpose (blocks
// 4096..4255). R12 version (best measured). ----
__global__ __launch_bounds__(256) void cvt_kernel(const float* __restrict__ x,
                                                  const float* __restrict__ Wq,
                                                  const float* __restrict__ Wk,
                                                  const float* __restrict__ Wv,
                                                  const float* __restrict__ Wo,
                                                  u16* __restrict__ xb,
                                                  u16* __restrict__ WT) {
  __shared__ u16 lds[64 * 66];
  int bid = blockIdx.x;
  if (bid < 4096) {
    int i = bid * 256 + threadIdx.x;
    float4 v = reinterpret_cast<const float4*>(x)[i];
    uint2 o = {pkbf(v.x, v.y), pkbf(v.z, v.w)};
    reinterpret_cast<uint2*>(xb)[i] = o;
  } else {
    int t = bid - 4096;           // 0..159
    int tn = t >> 3, tk = t & 7;  // tn 0..19 (n-tiles), tk 0..7 (k-tiles)
    int n0 = tn * 64, k0 = tk * 64;
    const float* src; int nc0, w;
    if (n0 < 512)      { src = Wq; nc0 = n0;       w = 512; }
    else if (n0 < 640) { src = Wk; nc0 = n0 - 512; w = 128; }
    else if (n0 < 768) { src = Wv; nc0 = n0 - 640; w = 128; }
    else               { src = Wo; nc0 = n0 - 768; w = 512; }
    int c = threadIdx.x & 63, r4 = threadIdx.x >> 6;
#pragma unroll
    for (int j = 0; j < 16; ++j) {
      int r = r4 + 4 * j;   // k-offset
      lds[c * 66 + r] = f2bf(src[(size_t)(k0 + r) * w + nc0 + c]);
    }
    __syncthreads();
#pragma unroll
    for (int j = 0; j < 16; ++j) {
      int cc = r4 + 4 * j;  // n-offset
      WT[(size_t)(n0 + cc) * 512 + k0 + c] = lds[cc * 66 + c];
    }
  }
}

// ---- fused QKV projection: 128x128 tile, BK=32, distance-2 register prefetch,
// LDS dbuf stride-40 (40 KB), 32x32 MFMA, 4 waves (2m x 2n), 2x2 acc/wave.
// R12 version (best measured). Q scaled by QSCALE; Q/K head-major
// [B,nh,S,64]; V TRANSPOSED [B,NKV,64,S].
__global__ __launch_bounds__(256, 2) void gemm_qkv_kernel(const u16* __restrict__ A,
                                                          const u16* __restrict__ WT,
                                                          const float* __restrict__ bq,
                                                          const float* __restrict__ bk,
                                                          const float* __restrict__ bv,
                                                          u16* __restrict__ Qb,
                                                          u16* __restrict__ Kb,
                                                          u16* __restrict__ Vt) {
  __shared__ __align__(16) u16 abuf[2][128 * 40];
  __shared__ __align__(16) u16 bbuf[2][128 * 40];
  int tid = threadIdx.x;
  int lane = tid & 63, wave = tid >> 6;
  int l31 = lane & 31, half = lane >> 5;
  int m0 = blockIdx.y * 128;
  int n0 = blockIdx.x * 128;
  int row = tid >> 2, ch = tid & 3;   // row 0..63, 4 chunks of 8 cover BK=32
  const u16* Asrc = A + (size_t)(m0 + row) * DMODEL + ch * 8;
  const u16* Bsrc = WT + (size_t)(n0 + row) * DMODEL + ch * 8;
  int wo = row * 40 + ch * 8;

  bf16x8 rA[2][2], rB[2][2];   // [slot][row-group g: rows r / r+64]
#pragma unroll
  for (int g = 0; g < 2; ++g) {
    rA[0][g] = *(const bf16x8*)(Asrc + (size_t)g * 64 * DMODEL);
    rB[0][g] = *(const bf16x8*)(Bsrc + (size_t)g * 64 * DMODEL);
    rA[1][g] = *(const bf16x8*)(Asrc + (size_t)g * 64 * DMODEL + 32);
    rB[1][g] = *(const bf16x8*)(Bsrc + (size_t)g * 64 * DMODEL + 32);
  }
#pragma unroll
  for (int g = 0; g < 2; ++g) {
    *(bf16x8*)(abuf[0] + wo + g * 64 * 40) = rA[0][g];
    *(bf16x8*)(bbuf[0] + wo + g * 64 * 40) = rB[0][g];
  }
  __syncthreads();

  floatx16 acc[2][2] = {{ZERO16, ZERO16}, {ZERO16, ZERO16}};
  int mw = (wave & 1) * 64, nw = (wave >> 1) * 64;
#pragma unroll 2
  for (int it = 0; it < 16; ++it) {
    if (it < 14) {
#pragma unroll
      for (int g = 0; g < 2; ++g) {
        rA[it & 1][g] = *(const bf16x8*)(Asrc + (size_t)g * 64 * DMODEL + (it + 2) * 32);
        rB[it & 1][g] = *(const bf16x8*)(Bsrc + (size_t)g * 64 * DMODEL + (it + 2) * 32);
      }
    }
    const u16* ab = abuf[it & 1];
    const u16* bbp = bbuf[it & 1];
#pragma unroll
    for (int ks = 0; ks < 2; ++ks) {
      int co = (2 * ks + half) * 8;
      bf16x8 a0 = *(const bf16x8*)(ab + (mw + l31) * 40 + co);
      bf16x8 a1 = *(const bf16x8*)(ab + (mw + 32 + l31) * 40 + co);
      bf16x8 b0 = *(const bf16x8*)(bbp + (nw + l31) * 40 + co);
      bf16x8 b1 = *(const bf16x8*)(bbp + (nw + 32 + l31) * 40 + co);
      acc[0][0] = MFMA32(a0, b0, acc[0][0], 0, 0, 0);
      acc[0][1] = MFMA32(a0, b1, acc[0][1], 0, 0, 0);
      acc[1][0] = MFMA32(a1, b0, acc[1][0], 0, 0, 0);
      acc[1][1] = MFMA32(a1, b1, acc[1][1], 0, 0, 0);
    }
    if (it < 15) {
#pragma unroll
      for (int g = 0; g < 2; ++g) {
        *(bf16x8*)(abuf[(it + 1) & 1] + wo + g * 64 * 40) = rA[(it + 1) & 1][g];
        *(bf16x8*)(bbuf[(it + 1) & 1] + wo + g * 64 * 40) = rB[(it + 1) & 1][g];
      }
    }
    __syncthreads();
  }

  int b4 = m0 >> 11;  // batch fixed per block (m-tile within one batch)
#pragma unroll
  for (int ns = 0; ns < 2; ++ns) {
    int col = n0 + nw + ns * 32 + l31;
    if (col >= 640) {
      // V: write transposed rows of Vt[b,kv,d,s] as ushort4 (4 consecutive s)
      int lc = col - 640;
      float bl = bv[lc];
      int hkv = lc >> 6, d = lc & 63;
      u16* vrow = Vt + ((size_t)(b4 * NKV + hkv) * HD + d) * SDIM;
#pragma unroll
      for (int ms = 0; ms < 2; ++ms) {
#pragma unroll
        for (int g = 0; g < 4; ++g) {
          int s = (m0 + mw + ms * 32 + 8 * g + 4 * half) & 2047;
          ushort4 t;
          t.x = f2bf(acc[ms][ns][4 * g + 0] + bl);
          t.y = f2bf(acc[ms][ns][4 * g + 1] + bl);
          t.z = f2bf(acc[ms][ns][4 * g + 2] + bl);
          t.w = f2bf(acc[ms][ns][4 * g + 3] + bl);
          *(ushort4*)(vrow + s) = t;
        }
      }
    } else {
      u16* outp; const float* bias; float scale; int nhreg, lc;
      if (col < 512) { outp = Qb; bias = bq; scale = QSCALE; nhreg = NH;  lc = col; }
      else           { outp = Kb; bias = bk; scale = 1.0f;   nhreg = NKV; lc = col - 512; }
      float bl = bias[lc];
      int h = lc >> 6, d = lc & 63;
      u16* base = outp + ((size_t)(b4 * nhreg + h) * SDIM) * HD + d;
#pragma unroll
      for (int ms = 0; ms < 2; ++ms) {
#pragma unroll
        for (int r = 0; r < 16; ++r) {
          int s = (m0 + mw + ms * 32 + (r & 3) + 8 * (r >> 2) + 4 * half) & 2047;
          base[(size_t)s * HD] = f2bf((acc[ms][ns][r] + bl) * scale);
        }
      }
    }
  }
}

// ---- O projection: 128x128 tile, BK=32, same pipeline, fp32 output ----
__global__ __launch_bounds__(256, 2) void gemm_out_kernel(const u16* __restrict__ A,
                                                          const u16* __restrict__ WTo,
                                                          const float* __restrict__ bo,
                                                          float* __restrict__ out) {
  __shared__ __align__(16) u16 abuf[2][128 * 40];
  __shared__ __align__(16) u16 bbuf[2][128 * 40];
  int tid = threadIdx.x;
  int lane = tid & 63, wave = tid >> 6;
  int l31 = lane & 31, half = lane >> 5;
  int m0 = blockIdx.y * 128;
  int n0 = blockIdx.x * 128;
  int row = tid >> 2, ch = tid & 3;
  const u16* Asrc = A + (size_t)(m0 + row) * DMODEL + ch * 8;
  const u16* Bsrc = WTo + (size_t)(n0 + row) * DMODEL + ch * 8;
  int wo = row * 40 + ch * 8;

  bf16x8 rA[2][2], rB[2][2];
#pragma unroll
  for (int g = 0; g < 2; ++g) {
    rA[0][g] = *(const bf16x8*)(Asrc + (size_t)g * 64 * DMODEL);
    rB[0][g] = *(const bf16x8*)(Bsrc + (size_t)g * 64 * DMODEL);
    rA[1][g] = *(const bf16x8*)(Asrc + (size_t)g * 64 * DMODEL + 32);
    rB[1][g] = *(const bf16x8*)(Bsrc + (size_t)g * 64 * DMODEL + 32);
  }
#pragma unroll
  for (int g = 0; g < 2; ++g) {
    *(bf16x8*)(abuf[0] + wo + g * 64 * 40) = rA[0][g];
    *(bf16x8*)(bbuf[0] + wo + g * 64 * 40) = rB[0][g];
  }
  __syncthreads();

  floatx16 acc[2][2] = {{ZERO16, ZERO16}, {ZERO16, ZERO16}};
  int mw = (wave & 1) * 64, nw = (wave >> 1) * 64;
#pragma unroll 2
  for (int it = 0; it < 16; ++it) {
    if (it < 14) {
#pragma unroll
      for (int g = 0; g < 2; ++g) {
        rA[it & 1][g] = *(const bf16x8*)(Asrc + (size_t)g * 64 * DMODEL + (it + 2) * 32);
        rB[it & 1][g] = *(const bf16x8*)(Bsrc + (size_t)g * 64 * DMODEL + (it + 2) * 32);
      }
    }
    const u16* ab = abuf[it & 1];
    const u16* bbp = bbuf[it & 1];
#pragma unroll
    for (int ks = 0; ks < 2; ++ks) {
      int co = (2 * ks + half) * 8;
      bf16x8 a0 = *(const bf16x8*)(ab + (mw + l31) * 40 + co);
      bf16x8 a1 = *(const bf16x8*)(ab + (mw + 32 + l31) * 40 + co);
      bf16x8 b0 = *(const bf16x8*)(bbp + (nw + l31) * 40 + co);
      bf16x8 b1 = *(const bf16x8*)(bbp + (nw + 32 + l31) * 40 + co);
      acc[0][0] = MFMA32(a0, b0, acc[0][0], 0, 0, 0);
      acc[0][1] = MFMA32(a0, b1, acc[0][1], 0, 0, 0);
      acc[1][0] = MFMA32(a1, b0, acc[1][0], 0, 0, 0);
      acc[1][1] = MFMA32(a1, b1, acc[1][1], 0, 0, 0);
    }
    if (it < 15) {
#pragma unroll
      for (int g = 0; g < 2; ++g) {
        *(bf16x8*)(abuf[(it + 1) & 1] + wo + g * 64 * 40) = rA[(it + 1) & 1][g];
        *(bf16x8*)(bbuf[(it + 1) & 1] + wo + g * 64 * 40) = rB[(it + 1) & 1][g];
      }
    }
    __syncthreads();
  }

#pragma unroll
  for (int ns = 0; ns < 2; ++ns) {
    int n = n0 + nw + ns * 32 + l31;
    float bl = bo[n];
#pragma unroll
    for (int ms = 0; ms < 2; ++ms) {
#pragma unroll
      for (int r = 0; r < 16; ++r) {
        int m = m0 + mw + ms * 32 + (r & 3) + 8 * (r >> 2) + 4 * half;
        out[(size_t)m * DMODEL + n] = acc[ms][ns][r] + bl;
      }
    }
  }
}

// ---- flash attention, 8-WAVE BLOCK (512 threads, 256 q-rows, grid 256 =
// 1 block/CU, same 2 waves/SIMD): ONE K/V staging per CU instead of two —
// per-thread staging ops halve (2 loads + 2 ds_writes vs 4+4), per-CU
// LDS-write traffic halves, K/V L2 re-reads halve. Thread t stages physical
// row r2=t>>3 (key 2*r2 if r2<32 else 2*r2-63 — same even/odd interleave),
// so all per-wave fragment reads, pipeline (PV(t) || QK(t+1)+exp, K dbuf,
// V tri-buf, 1 barrier/iter), setprio, and epilogue are R14-identical.
__global__ __launch_bounds__(512, 1) void attn_kernel(const u16* __restrict__ Q,
                                                      const u16* __restrict__ K,
                                                      const u16* __restrict__ Vt,
                                                      u16* __restrict__ O) {
  __shared__ __align__(16) u16 kbuf[2][64 * 72];
  __shared__ __align__(16) u16 vbuf[3][64 * 72];
  int tid = threadIdx.x;
  int lane = tid & 63, wave = tid >> 6;
  int l31 = lane & 31, half = lane >> 5;
  int bh = blockIdx.y;
  int b = bh >> 3, h = bh & 7, kv = h >> 2;
  int q0 = blockIdx.x * 256 + wave * 32;
  const u16* Qh = Q + (size_t)(b * NH + h) * SDIM * HD;
  const u16* Kh = K + (size_t)(b * NKV + kv) * SDIM * HD;
  const u16* Vh = Vt + (size_t)(b * NKV + kv) * HD * SDIM;

  bf16x8 qf[4];
#pragma unroll
  for (int ks = 0; ks < 4; ++ks)
    qf[ks] = *(const bf16x8*)(Qh + (size_t)(q0 + l31) * HD + ks * 16 + half * 8);

  // staging: 512 threads cover 64 rows x 8 chunks, one K + one V row-chunk each
  int ch = tid & 7, r2 = tid >> 3;           // r2 0..63
  int gk = r2 < 32 ? 2 * r2 : 2 * r2 - 63;   // even/odd key (or d) interleave
  const u16* Ks0 = Kh + (size_t)gk * HD + ch * 8;
  const u16* Vs0 = Vh + (size_t)gk * SDIM + ch * 8;
  int w0 = r2 * 72 + ch * 8;

  {
    bf16x8 k0 = *(const bf16x8*)Ks0;
    bf16x8 v0 = *(const bf16x8*)Vs0;
    *(bf16x8*)(kbuf[0] + w0) = k0;
    *(bf16x8*)(vbuf[0] + w0) = v0;
  }
  bf16x8 sK0 = *(const bf16x8*)(Ks0 + 4096);
  bf16x8 sV0 = *(const bf16x8*)(Vs0 + 64);
  __syncthreads();

  floatx16 o0 = ZERO16, o1 = ZERO16;
  float sml = 0.0f;
  u32 pk[16];

  // prologue: QK(0) + exp + pack
  {
    floatx16 sa = ZERO16, sb = ZERO16;
#pragma unroll
    for (int ks = 0; ks < 4; ++ks) {
      int co = (2 * ks + half) * 8;
      bf16x8 kf0 = *(const bf16x8*)(kbuf[0] + l31 * 72 + co);
      bf16x8 kf1 = *(const bf16x8*)(kbuf[0] + (32 + l31) * 72 + co);
      sa = MFMA32(kf0, qf[ks], sa, 0, 0, 0);
      sb = MFMA32(kf1, qf[ks], sb, 0, 0, 0);
    }
#pragma unroll
    for (int r = 0; r < 16; ++r) {
      float p0 = __builtin_amdgcn_exp2f(sa[r]);
      float p1 = __builtin_amdgcn_exp2f(sb[r]);
      sml += p0 + p1;
      pk[r] = pkbf(p0, p1);
    }
  }

  int vp = 0;  // v-read parity for iter t
  for (int t = 0; t < 32; ++t) {
    int wp = vp + 1; if (wp == 3) wp = 0;   // v-write parity = (t+1)%3
    int kp = (t + 1) & 1;                   // k write+read parity for tile t+1
    if (t < 31) {
      *(bf16x8*)(kbuf[kp] + w0) = sK0;
      *(bf16x8*)(vbuf[wp] + w0) = sV0;
    }
    if (t < 30) {
      sK0 = *(const bf16x8*)(Ks0 + (size_t)(t + 2) * 4096);
      sV0 = *(const bf16x8*)(Vs0 + (t + 2) * 64);
    }
    __syncthreads();

    __builtin_amdgcn_s_setprio(1);
    // PV(t): A-frag kc = pk[4kc+0..3] (lane-local), V from vbuf[vp]
    const u16* vb = vbuf[vp];
#pragma unroll
    for (int kc = 0; kc < 4; ++kc) {
      int co = (2 * kc + half) * 8;
      union { u32 u[4]; bf16x8 v; } pf;
      pf.u[0] = pk[4 * kc + 0]; pf.u[1] = pk[4 * kc + 1];
      pf.u[2] = pk[4 * kc + 2]; pf.u[3] = pk[4 * kc + 3];
      bf16x8 vf0 = *(const bf16x8*)(vb + l31 * 72 + co);
      bf16x8 vf1 = *(const bf16x8*)(vb + (32 + l31) * 72 + co);
      o0 = MFMA32(pf.v, vf0, o0, 0, 0, 0);
      o1 = MFMA32(pf.v, vf1, o1, 0, 0, 0);
    }

    // QK(t+1) + exp + pack, overlapped with PV(t) above (independent)
    if (t < 31) {
      const u16* kb = kbuf[kp];
      floatx16 sa = ZERO16, sb = ZERO16;
#pragma unroll
      for (int ks = 0; ks < 4; ++ks) {
        int co = (2 * ks + half) * 8;
        bf16x8 kf0 = *(const bf16x8*)(kb + l31 * 72 + co);
        bf16x8 kf1 = *(const bf16x8*)(kb + (32 + l31) * 72 + co);
        sa = MFMA32(kf0, qf[ks], sa, 0, 0, 0);
        sb = MFMA32(kf1, qf[ks], sb, 0, 0, 0);
      }
      __builtin_amdgcn_s_setprio(0);
      u32 pknew[16];
#pragma unroll
      for (int r = 0; r < 16; ++r) {
        float p0 = __builtin_amdgcn_exp2f(sa[r]);
        float p1 = __builtin_amdgcn_exp2f(sb[r]);
        sml += p0 + p1;
        pknew[r] = pkbf(p0, p1);
      }
#pragma unroll
      for (int r = 0; r < 16; ++r) pk[r] = pknew[r];
    } else {
      __builtin_amdgcn_s_setprio(0);
    }
    vp = wp;
  }

  sml += __shfl_xor(sml, 32);

#pragma unroll
  for (int r = 0; r < 16; ++r) {
    int q = (r & 3) + 8 * (r >> 2) + 4 * half;
    float inv = 1.0f / __shfl(sml, q);
    int s = q0 + q;
    u32* dst = (u32*)(O + ((size_t)(b * SDIM + s) * DMODEL + h * HD));
    dst[l31] = pkbf(o0[r] * inv, o1[r] * inv);
  }
}

extern "C" void kernel_launch(void* const* d_in, const int* in_sizes, int n_in,
                              void* d_out, int out_size, void* d_ws, size_t ws_size,
                              hipStream_t stream) {
  const float* x  = (const float*)d_in[0];
  const float* Wq = (const float*)d_in[1];
  const float* bq = (const float*)d_in[2];
  const float* Wk = (const float*)d_in[3];
  const float* bk = (const float*)d_in[4];
  const float* Wv = (const float*)d_in[5];
  const float* bv = (const float*)d_in[6];
  const float* Wo = (const float*)d_in[7];
  const float* bo = (const float*)d_in[8];
  float* out = (float*)d_out;

  const size_t M = (size_t)BATCH * SDIM;  // 8192
  u16* xb  = (u16*)d_ws;                  // 8192*512
  u16* WT  = xb  + M * DMODEL;            // 1280*512
  u16* Qb  = WT  + 1280 * DMODEL;         // 8192*512  [B,NH,S,64]
  u16* Kb  = Qb  + M * DMODEL;            // 8192*128  [B,NKV,S,64]
  u16* VtB = Kb  + M * 128;               // 8192*128  [B,NKV,64,S]
  u16* Ab  = VtB + M * 128;               // 8192*512  [B,S,512]

  cvt_kernel<<<4096 + 160, 256, 0, stream>>>(x, Wq, Wk, Wv, Wo, xb, WT);
  gemm_qkv_kernel<<<dim3(768 / 128, M / 128), 256, 0, stream>>>(xb, WT, bq, bk, bv, Qb, Kb, VtB);
  attn_kernel<<<dim3(SDIM / 256, BATCH * NH), 512, 0, stream>>>(Qb, Kb, VtB, Ab);
  gemm_out_kernel<<<dim3(512 / 128, M / 128), 256, 0, stream>>>(Ab, WT + (size_t)768 * DMODEL, bo, out);
}